// Round 15
// baseline (193.167 us; speedup 1.0000x reference)
//
#include <hip/hip_runtime.h>
#include <hip/hip_bf16.h>
#include <math.h>

typedef __bf16 bf16_t;
typedef __bf16 bf16x8 __attribute__((ext_vector_type(8)));
typedef __bf16 bf16x4 __attribute__((ext_vector_type(4)));
typedef float  f32x4  __attribute__((ext_vector_type(4)));

#define GLD_LDS16(g, l)                                                          \
  __builtin_amdgcn_global_load_lds((const __attribute__((address_space(1))) void*)(g), \
                                   (__attribute__((address_space(3))) void*)(l), 16, 0, 0)

// ---------------- fused converts ----------------
__global__ __launch_bounds__(256) void k_cvt_all(const float* __restrict__ leaves,
                                                 const float* __restrict__ V_w,
                                                 const float* __restrict__ O_w,
                                                 const float* __restrict__ U_w,
                                                 const float* __restrict__ W_w,
                                                 const float* __restrict__ U_b,
                                                 const float* __restrict__ W_b,
                                                 bf16_t* __restrict__ leaves_bf,
                                                 bf16_t* __restrict__ Vw_bf,
                                                 bf16_t* __restrict__ Ow_bf,
                                                 bf16_t* __restrict__ UW_bf,
                                                 float* __restrict__ buw) {
  const int gtid = blockIdx.x * 256 + threadIdx.x;
  const int G = gridDim.x * 256;
  for (int i = gtid; i < 2097152; i += G) {            // leaves: 8M elems / 4
    float4 v = reinterpret_cast<const float4*>(leaves)[i];
    bf16x4 o; o[0] = (bf16_t)v.x; o[1] = (bf16_t)v.y; o[2] = (bf16_t)v.z; o[3] = (bf16_t)v.w;
    reinterpret_cast<bf16x4*>(leaves_bf)[i] = o;
  }
  for (int i = gtid; i < 262144; i += G) {             // V_w
    float4 v = reinterpret_cast<const float4*>(V_w)[i];
    bf16x4 o; o[0] = (bf16_t)v.x; o[1] = (bf16_t)v.y; o[2] = (bf16_t)v.z; o[3] = (bf16_t)v.w;
    reinterpret_cast<bf16x4*>(Vw_bf)[i] = o;
  }
  for (int i = gtid; i < 262144; i += G) {             // O_w
    float4 v = reinterpret_cast<const float4*>(O_w)[i];
    bf16x4 o; o[0] = (bf16_t)v.x; o[1] = (bf16_t)v.y; o[2] = (bf16_t)v.z; o[3] = (bf16_t)v.w;
    reinterpret_cast<bf16x4*>(Ow_bf)[i] = o;
  }
  for (int idx = gtid; idx < 524288; idx += G) {       // UW = [U|W] concat along K
    int i = idx * 4;
    int g = i >> 11;
    int k = i & 2047;
    const float* src = (k < 1024) ? (U_w + g * 1024 + k) : (W_w + g * 1024 + (k - 1024));
    float4 v = *reinterpret_cast<const float4*>(src);
    bf16x4 o; o[0] = (bf16_t)v.x; o[1] = (bf16_t)v.y; o[2] = (bf16_t)v.z; o[3] = (bf16_t)v.w;
    reinterpret_cast<bf16x4*>(UW_bf)[idx] = o;
  }
  if (gtid < 1024) buw[gtid] = U_b[gtid] + W_b[gtid];
}

// ---------------- GEMM: 64x128 tile, BK=64, NB=3 depth-2, 3-bit XOR swizzle --------
// 16 MFMA per barrier; half the per-step overhead of BK=32 (round-14 proven lever).
// Row stride 64 bf16 = 128 B -> XOR across all 8 chunks/row: ch ^= (r>>1)&7
// (2 lanes/bank = free). Inverse swizzle on global source keeps rows coalesced.
// Row-guarded P stores allow M < TM.
template <bool SPLIT>
__global__ __launch_bounds__(256, 2) void k_gemm64(
    const bf16_t* __restrict__ A, const bf16_t* __restrict__ Bw,
    const float* __restrict__ bias, bf16_t* __restrict__ C,
    bf16_t* __restrict__ P, int M, int Kstride, int kchunk) {
  constexpr int VM = 6;                       // loads/thread/stage: A 2 + B 4
  constexpr int NB = 3;                       // 72 KB LDS -> 2 blocks/CU
  __shared__ bf16_t As[NB][64 * 64];
  __shared__ bf16_t Bs[NB][128 * 64];

  const int tid = threadIdx.x;
  const int lane = tid & 63;
  const int wave = tid >> 6;
  const int wr = wave >> 1, wc = wave & 1;
  const int bm = blockIdx.x, bn = blockIdx.y, bz = blockIdx.z;

  const bf16_t* Abase = A + (size_t)bm * 64 * Kstride + (size_t)bz * kchunk;
  const bf16_t* Bbase = Bw + (size_t)bn * 128 * Kstride + (size_t)bz * kchunk;

  f32x4 acc[2][4] = {};
  const int rl = lane & 15, kq = lane >> 4;

  auto stage = [&](int buf, int ko) {
#pragma unroll
    for (int it = 0; it < 2; ++it) {          // A: 64 rows x 8 chunks = 512
      int c = tid + 256 * it;
      int r = c >> 3, ch = c & 7;
      int kb = ch ^ ((r >> 1) & 7);           // inverse 3-bit swizzle on source
      GLD_LDS16(Abase + (size_t)r * Kstride + ko + kb * 8, &As[buf][c * 8]);
    }
#pragma unroll
    for (int it = 0; it < 4; ++it) {          // B: 128 rows x 8 chunks = 1024
      int c = tid + 256 * it;
      int r = c >> 3, ch = c & 7;
      int kb = ch ^ ((r >> 1) & 7);
      GLD_LDS16(Bbase + (size_t)r * Kstride + ko + kb * 8, &Bs[buf][c * 8]);
    }
  };

  const int kiters = kchunk >> 6;
  stage(0, 0);
  if (kiters > 1) stage(1, 64);

  int cur = 0;
  for (int t = 0; t < kiters; ++t) {
    const int nin = kiters - 1 - t;
    if (nin >= 1) asm volatile("s_waitcnt vmcnt(%0)" :: "i"(VM) : "memory");
    else          asm volatile("s_waitcnt vmcnt(0)" ::: "memory");
    __builtin_amdgcn_s_barrier();
    __builtin_amdgcn_sched_barrier(0);
    if (t + 2 < kiters) {
      int b2 = cur + 2; if (b2 >= 3) b2 -= 3;
      stage(b2, (t + 2) * 64);
    }
#pragma unroll
    for (int kk = 0; kk < 2; ++kk) {          // two K=32 windows per tile
      bf16x8 af[2], bfr[4];
#pragma unroll
      for (int i = 0; i < 2; ++i) {
        int r = wr * 32 + i * 16 + rl;
        int ch = ((kk << 2) | kq) ^ ((r >> 1) & 7);
        af[i] = *reinterpret_cast<const bf16x8*>(&As[cur][r * 64 + ch * 8]);
      }
#pragma unroll
      for (int j = 0; j < 4; ++j) {
        int r = wc * 64 + j * 16 + rl;
        int ch = ((kk << 2) | kq) ^ ((r >> 1) & 7);
        bfr[j] = *reinterpret_cast<const bf16x8*>(&Bs[cur][r * 64 + ch * 8]);
      }
#pragma unroll
      for (int i = 0; i < 2; ++i)
#pragma unroll
        for (int j = 0; j < 4; ++j)
          acc[i][j] = __builtin_amdgcn_mfma_f32_16x16x32_bf16(af[i], bfr[j], acc[i][j], 0, 0, 0);
    }
    if (++cur >= 3) cur = 0;
  }

  const int rq = lane >> 4, cl = lane & 15;
  if (SPLIT) {
    bf16_t* Pp = P + (size_t)bz * M * 1024;
#pragma unroll
    for (int j = 0; j < 4; ++j) {
      int gcol = bn * 128 + wc * 64 + j * 16 + cl;
#pragma unroll
      for (int i = 0; i < 2; ++i) {
        int grow = bm * 64 + wr * 32 + i * 16 + rq * 4;
#pragma unroll
        for (int reg = 0; reg < 4; ++reg)
          if (grow + reg < M)
            Pp[(size_t)(grow + reg) * 1024 + gcol] = (bf16_t)acc[i][j][reg];
      }
    }
  } else {
#pragma unroll
    for (int j = 0; j < 4; ++j) {
      int gcol = bn * 128 + wc * 64 + j * 16 + cl;
      float bv = bias[gcol];
#pragma unroll
      for (int i = 0; i < 2; ++i) {
        int grow = bm * 64 + wr * 32 + i * 16 + rq * 4;
#pragma unroll
        for (int reg = 0; reg < 4; ++reg) {
          float v = acc[i][j][reg] + bv;
          v = v > 0.0f ? v : 0.0f;
          C[(size_t)(grow + reg) * 1024 + gcol] = (bf16_t)v;
        }
      }
    }
  }
}

// ---------------- split-K reduce: C = relu(sum_z P[z] + bias), bf16 partials --------
__global__ __launch_bounds__(256) void k_reduce(const bf16_t* __restrict__ P,
                                                const float* __restrict__ bias,
                                                bf16_t* __restrict__ C, int M, int ks) {
  constexpr int N = 1024;
  int idx = blockIdx.x * 256 + threadIdx.x;
  int col = (idx * 4) & (N - 1);
  int row = (idx * 4) >> 10;
  float s0 = 0.0f, s1 = 0.0f, s2 = 0.0f, s3 = 0.0f;
  for (int z = 0; z < ks; ++z) {
    bf16x4 v = *reinterpret_cast<const bf16x4*>(P + ((size_t)z * M + row) * N + col);
    s0 += (float)v[0]; s1 += (float)v[1]; s2 += (float)v[2]; s3 += (float)v[3];
  }
  float4 b = *reinterpret_cast<const float4*>(bias + col);
  bf16x4 o;
  o[0] = (bf16_t)fmaxf(s0 + b.x, 0.0f);
  o[1] = (bf16_t)fmaxf(s1 + b.y, 0.0f);
  o[2] = (bf16_t)fmaxf(s2 + b.z, 0.0f);
  o[3] = (bf16_t)fmaxf(s3 + b.w, 0.0f);
  reinterpret_cast<bf16x4*>(C)[idx] = o;
}

// ---------------- small-M GEMV (M<=16): wave computes 8 rows x 1 col ----------------
template <int KK, bool RELU, bool F32OUT>
__global__ __launch_bounds__(256) void k_tail(const bf16_t* __restrict__ A,
                                              const bf16_t* __restrict__ Bw,
                                              const float* __restrict__ bias,
                                              void* __restrict__ Cout, int M) {
  constexpr int N = 1024;
  constexpr int KPL = KK / 64;
  const int lane = threadIdx.x & 63;
  const int gw = blockIdx.x * 4 + (threadIdx.x >> 6);
  const int n = gw & (N - 1);
  const int mbase = (gw >> 10) * 8;
  const int k0 = lane * KPL;

  float bv[KPL];
  const bf16_t* bp = Bw + (size_t)n * KK + k0;
#pragma unroll
  for (int q = 0; q < KPL / 8; ++q) {
    bf16x8 v = *reinterpret_cast<const bf16x8*>(bp + q * 8);
#pragma unroll
    for (int j = 0; j < 8; ++j) bv[q * 8 + j] = (float)v[j];
  }

  float acc[8];
#pragma unroll
  for (int m = 0; m < 8; ++m) {
    const bf16_t* ap = A + (size_t)(mbase + m) * KK + k0;
    float s = 0.0f;
#pragma unroll
    for (int q = 0; q < KPL / 8; ++q) {
      bf16x8 v = *reinterpret_cast<const bf16x8*>(ap + q * 8);
#pragma unroll
      for (int j = 0; j < 8; ++j) s += (float)v[j] * bv[q * 8 + j];
    }
    acc[m] = s;
  }
#pragma unroll
  for (int m = 0; m < 8; ++m) {
#pragma unroll
    for (int off = 32; off >= 1; off >>= 1) acc[m] += __shfl_xor(acc[m], off, 64);
  }
  if (lane < 8 && mbase + lane < M) {
    float v = acc[lane] + bias[n];
    if (RELU) v = v > 0.0f ? v : 0.0f;
    if (F32OUT) ((float*)Cout)[(size_t)(mbase + lane) * N + n] = v;
    else        ((bf16_t*)Cout)[(size_t)(mbase + lane) * N + n] = (bf16_t)v;
  }
}

// ---------------- log_softmax over 8 rows x 1024 (tiny) ----------------
__global__ __launch_bounds__(256) void k_logsoftmax(const float* __restrict__ logits,
                                                    float* __restrict__ out) {
  int b = blockIdx.x;
  const float* x = logits + b * 1024;
  int tid = threadIdx.x;
  int wave = tid >> 6, lane = tid & 63;
  __shared__ float red[8];

  float m = -1e30f;
  for (int i = tid; i < 1024; i += 256) m = fmaxf(m, x[i]);
#pragma unroll
  for (int off = 32; off >= 1; off >>= 1) m = fmaxf(m, __shfl_xor(m, off, 64));
  if (lane == 0) red[wave] = m;
  __syncthreads();
  m = fmaxf(fmaxf(red[0], red[1]), fmaxf(red[2], red[3]));
  float s = 0.0f;
  for (int i = tid; i < 1024; i += 256) s += expf(x[i] - m);
#pragma unroll
  for (int off = 32; off >= 1; off >>= 1) s += __shfl_xor(s, off, 64);
  if (lane == 0) red[wave] = s;
  __syncthreads();
  float lse = m + logf(red[0] + red[1] + red[2] + red[3]);
  for (int i = tid; i < 1024; i += 256) out[b * 1024 + i] = x[i] - lse;
}

// ---------------- launch ----------------
extern "C" void kernel_launch(void* const* d_in, const int* in_sizes, int n_in,
                              void* d_out, int out_size, void* d_ws, size_t ws_size,
                              hipStream_t stream) {
  const float* leaves = (const float*)d_in[0];
  const float* V_w = (const float*)d_in[1];
  const float* V_b = (const float*)d_in[2];
  const float* U_w = (const float*)d_in[3];
  const float* U_b = (const float*)d_in[4];
  const float* W_w = (const float*)d_in[5];
  const float* W_b = (const float*)d_in[6];
  const float* O_w = (const float*)d_in[7];
  const float* O_b = (const float*)d_in[8];
  float* out = (float*)d_out;

  char* ws = (char*)d_ws;
  size_t off = 0;
  auto alloc = [&](size_t bytes) -> void* {
    off = (off + 255) & ~(size_t)255;
    void* p = ws + off;
    off += bytes;
    return p;
  };

  const size_t MB16 = (size_t)8192 * 1024 * 2;
  bf16_t* leaves_bf = (bf16_t*)alloc(MB16);
  bf16_t* Vw_bf = (bf16_t*)alloc((size_t)1024 * 1024 * 2);
  bf16_t* UW_bf = (bf16_t*)alloc((size_t)2 * 1024 * 1024 * 2);
  bf16_t* Ow_bf = (bf16_t*)alloc((size_t)1024 * 1024 * 2);
  float* buw = (float*)alloc(1024 * 4);
  bf16_t* hA = (bf16_t*)alloc(MB16);
  float* logits = (float*)alloc(8 * 1024 * 4);
  bf16_t* Pbuf = (bf16_t*)alloc((size_t)8 * 4096 * 1024 * 2);   // bf16 partials
  (void)ws_size; (void)in_sizes; (void)n_in; (void)out_size;

  // 1: fused converts
  k_cvt_all<<<2048, 256, 0, stream>>>(leaves, V_w, O_w, U_w, W_w, U_b, W_b,
                                      leaves_bf, Vw_bf, Ow_bf, UW_bf, buw);

  // 2: L0 GEMM 8192x1024, K=1024, BK=64 -> grid(128,8) = 1024 blocks, 16 steps
  k_gemm64<false><<<dim3(128, 8), 256, 0, stream>>>(
      leaves_bf, Vw_bf, V_b, hA, nullptr, 8192, 1024, 1024);

  bf16_t* src = hA;
  bf16_t* dst = leaves_bf;
  auto swap = [&]() { bf16_t* t = src; src = dst; dst = t; };

  // 3: M=4096, K=2048, BK=64 split-K2 -> grid(64,8,2) = 1024 blocks, 16 steps
  k_gemm64<true><<<dim3(64, 8, 2), 256, 0, stream>>>(
      src, UW_bf, nullptr, nullptr, Pbuf, 4096, 2048, 1024);
  k_reduce<<<4096 * 1024 / 4 / 256, 256, 0, stream>>>(Pbuf, buw, dst, 4096, 2);
  swap();
  // 4: M=2048 BK=64 split-K2 -> grid(32,8,2) = 512 blocks, 16 steps
  k_gemm64<true><<<dim3(32, 8, 2), 256, 0, stream>>>(
      src, UW_bf, nullptr, nullptr, Pbuf, 2048, 2048, 1024);
  k_reduce<<<2048 * 1024 / 4 / 256, 256, 0, stream>>>(Pbuf, buw, dst, 2048, 2);
  swap();
  // 5: M=1024 BK=64 split-K4 -> 512 blocks, 8 steps
  k_gemm64<true><<<dim3(16, 8, 4), 256, 0, stream>>>(
      src, UW_bf, nullptr, nullptr, Pbuf, 1024, 2048, 512);
  k_reduce<<<1024 * 1024 / 4 / 256, 256, 0, stream>>>(Pbuf, buw, dst, 1024, 4);
  swap();
  // 6: M=512 BK=64 split-K4 -> 256 blocks
  k_gemm64<true><<<dim3(8, 8, 4), 256, 0, stream>>>(
      src, UW_bf, nullptr, nullptr, Pbuf, 512, 2048, 512);
  k_reduce<<<512 * 1024 / 4 / 256, 256, 0, stream>>>(Pbuf, buw, dst, 512, 4);
  swap();
  // 7: M=256 BK=64 split-K8 -> 256 blocks, 4 steps
  k_gemm64<true><<<dim3(4, 8, 8), 256, 0, stream>>>(
      src, UW_bf, nullptr, nullptr, Pbuf, 256, 2048, 256);
  k_reduce<<<256 * 1024 / 4 / 256, 256, 0, stream>>>(Pbuf, buw, dst, 256, 8);
  swap();
  // 8: M=128 BK=64 split-K8 -> 128 blocks
  k_gemm64<true><<<dim3(2, 8, 8), 256, 0, stream>>>(
      src, UW_bf, nullptr, nullptr, Pbuf, 128, 2048, 256);
  k_reduce<<<128 * 1024 / 4 / 256, 256, 0, stream>>>(Pbuf, buw, dst, 128, 8);
  swap();
  // 9: M=64 BK=64 split-K16 -> 128 blocks, 2 steps
  k_gemm64<true><<<dim3(1, 8, 16), 256, 0, stream>>>(
      src, UW_bf, nullptr, nullptr, Pbuf, 64, 2048, 128);
  k_reduce<<<64 * 1024 / 4 / 256, 256, 0, stream>>>(Pbuf, buw, dst, 64, 16);
  swap();
  // 10: M=32 BK=64 split-K16 (row-guarded) -> 128 blocks
  k_gemm64<true><<<dim3(1, 8, 16), 256, 0, stream>>>(
      src, UW_bf, nullptr, nullptr, Pbuf, 32, 2048, 128);
  k_reduce<<<32 * 1024 / 4 / 256, 256, 0, stream>>>(Pbuf, buw, dst, 32, 16);
  swap();
  // 11-12: tails M=16, 8
  for (int M = 16; M >= 8; M >>= 1) {
    int blocks = (M / 8) * 1024 / 4;
    k_tail<2048, true, false><<<blocks, 256, 0, stream>>>(src, UW_bf, buw, dst, M);
    swap();
  }

  // 13: logits (M=8, K=1024, fp32 out) -> 256 blocks
  k_tail<1024, false, true><<<256, 256, 0, stream>>>(src, Ow_bf, O_b, logits, 8);
  // 14: log_softmax
  k_logsoftmax<<<8, 256, 0, stream>>>(logits, out);
}

// Round 16
// 187.836 us; speedup vs baseline: 1.0284x; 1.0284x over previous
//
#include <hip/hip_runtime.h>
#include <hip/hip_bf16.h>
#include <math.h>

typedef __bf16 bf16_t;
typedef __bf16 bf16x8 __attribute__((ext_vector_type(8)));
typedef __bf16 bf16x4 __attribute__((ext_vector_type(4)));
typedef float  f32x4  __attribute__((ext_vector_type(4)));

#define GLD_LDS16(g, l)                                                          \
  __builtin_amdgcn_global_load_lds((const __attribute__((address_space(1))) void*)(g), \
                                   (__attribute__((address_space(3))) void*)(l), 16, 0, 0)

// ---------------- fused converts ----------------
__global__ __launch_bounds__(256) void k_cvt_all(const float* __restrict__ leaves,
                                                 const float* __restrict__ V_w,
                                                 const float* __restrict__ O_w,
                                                 const float* __restrict__ U_w,
                                                 const float* __restrict__ W_w,
                                                 const float* __restrict__ U_b,
                                                 const float* __restrict__ W_b,
                                                 bf16_t* __restrict__ leaves_bf,
                                                 bf16_t* __restrict__ Vw_bf,
                                                 bf16_t* __restrict__ Ow_bf,
                                                 bf16_t* __restrict__ UW_bf,
                                                 float* __restrict__ buw) {
  const int gtid = blockIdx.x * 256 + threadIdx.x;
  const int G = gridDim.x * 256;
  for (int i = gtid; i < 2097152; i += G) {            // leaves: 8M elems / 4
    float4 v = reinterpret_cast<const float4*>(leaves)[i];
    bf16x4 o; o[0] = (bf16_t)v.x; o[1] = (bf16_t)v.y; o[2] = (bf16_t)v.z; o[3] = (bf16_t)v.w;
    reinterpret_cast<bf16x4*>(leaves_bf)[i] = o;
  }
  for (int i = gtid; i < 262144; i += G) {             // V_w
    float4 v = reinterpret_cast<const float4*>(V_w)[i];
    bf16x4 o; o[0] = (bf16_t)v.x; o[1] = (bf16_t)v.y; o[2] = (bf16_t)v.z; o[3] = (bf16_t)v.w;
    reinterpret_cast<bf16x4*>(Vw_bf)[i] = o;
  }
  for (int i = gtid; i < 262144; i += G) {             // O_w
    float4 v = reinterpret_cast<const float4*>(O_w)[i];
    bf16x4 o; o[0] = (bf16_t)v.x; o[1] = (bf16_t)v.y; o[2] = (bf16_t)v.z; o[3] = (bf16_t)v.w;
    reinterpret_cast<bf16x4*>(Ow_bf)[i] = o;
  }
  for (int idx = gtid; idx < 524288; idx += G) {       // UW = [U|W] concat along K
    int i = idx * 4;
    int g = i >> 11;
    int k = i & 2047;
    const float* src = (k < 1024) ? (U_w + g * 1024 + k) : (W_w + g * 1024 + (k - 1024));
    float4 v = *reinterpret_cast<const float4*>(src);
    bf16x4 o; o[0] = (bf16_t)v.x; o[1] = (bf16_t)v.y; o[2] = (bf16_t)v.z; o[3] = (bf16_t)v.w;
    reinterpret_cast<bf16x4*>(UW_bf)[idx] = o;
  }
  if (gtid < 1024) buw[gtid] = U_b[gtid] + W_b[gtid];
}

// ---------------- big GEMM: 128x128, BK=32, NB=5 depth-4 (best for L0/M4096) -------
// Round-15 lesson: BK=64 64x128 here REGRESSES (+5us): 2x B-panel L2 traffic
// (1024 vs 512 blocks) and depth 4->2. Keep BK=32 128^2 for the big shapes.
template <bool SPLIT>
__global__ __launch_bounds__(256, 2) void k_gemm(
    const bf16_t* __restrict__ A, const bf16_t* __restrict__ Bw,
    const float* __restrict__ bias, bf16_t* __restrict__ C,
    bf16_t* __restrict__ P, int M, int Kstride, int kchunk) {
  constexpr int NB = 5;
  constexpr int VMS = 4;                      // loads/thread/stage: A 2 + B 2
  __shared__ bf16_t As[NB][128 * 32];
  __shared__ bf16_t Bs[NB][128 * 32];

  const int tid = threadIdx.x;
  const int lane = tid & 63;
  const int wave = tid >> 6;
  const int wr = wave >> 1, wc = wave & 1;
  const int bm = blockIdx.x, bn = blockIdx.y, bz = blockIdx.z;

  const bf16_t* Abase = A + (size_t)bm * 128 * Kstride + (size_t)bz * kchunk;
  const bf16_t* Bbase = Bw + (size_t)bn * 128 * Kstride + (size_t)bz * kchunk;

  f32x4 acc[4][4] = {};
  const int rl = lane & 15, kq = lane >> 4;

  auto stage = [&](int buf, int ko) {
#pragma unroll
    for (int it = 0; it < 2; ++it) {
      int c = tid + 256 * it;
      int r = c >> 2, kbp = c & 3;
      int kb = kbp ^ ((r >> 1) & 3);
      GLD_LDS16(Abase + (size_t)r * Kstride + ko + kb * 8, &As[buf][c * 8]);
    }
#pragma unroll
    for (int it = 0; it < 2; ++it) {
      int c = tid + 256 * it;
      int r = c >> 2, kbp = c & 3;
      int kb = kbp ^ ((r >> 1) & 3);
      GLD_LDS16(Bbase + (size_t)r * Kstride + ko + kb * 8, &Bs[buf][c * 8]);
    }
  };

  const int kiters = kchunk >> 5;
  stage(0, 0);
  if (kiters > 1) stage(1, 32);
  if (kiters > 2) stage(2, 64);
  if (kiters > 3) stage(3, 96);

  int cur = 0;
  for (int t = 0; t < kiters; ++t) {
    const int nin = kiters - 1 - t;
    if (nin >= 3)      asm volatile("s_waitcnt vmcnt(%0)" :: "i"(3 * VMS) : "memory");
    else if (nin == 2) asm volatile("s_waitcnt vmcnt(%0)" :: "i"(2 * VMS) : "memory");
    else if (nin == 1) asm volatile("s_waitcnt vmcnt(%0)" :: "i"(VMS) : "memory");
    else               asm volatile("s_waitcnt vmcnt(0)" ::: "memory");
    __builtin_amdgcn_s_barrier();
    __builtin_amdgcn_sched_barrier(0);
    if (t + NB - 1 < kiters) {
      int bnx = cur + NB - 1; if (bnx >= NB) bnx -= NB;
      stage(bnx, (t + NB - 1) * 32);
    }
    bf16x8 af[4], bfr[4];
#pragma unroll
    for (int i = 0; i < 4; ++i) {
      int r = wr * 64 + i * 16 + rl;
      int kbp = kq ^ ((r >> 1) & 3);
      af[i] = *reinterpret_cast<const bf16x8*>(&As[cur][r * 32 + kbp * 8]);
    }
#pragma unroll
    for (int j = 0; j < 4; ++j) {
      int r = wc * 64 + j * 16 + rl;
      int kbp = kq ^ ((r >> 1) & 3);
      bfr[j] = *reinterpret_cast<const bf16x8*>(&Bs[cur][r * 32 + kbp * 8]);
    }
#pragma unroll
    for (int i = 0; i < 4; ++i)
#pragma unroll
      for (int j = 0; j < 4; ++j)
        acc[i][j] = __builtin_amdgcn_mfma_f32_16x16x32_bf16(af[i], bfr[j], acc[i][j], 0, 0, 0);
    if (++cur >= NB) cur = 0;
  }

  const int rq = lane >> 4, cl = lane & 15;
  if (SPLIT) {
    bf16_t* Pp = P + (size_t)bz * M * 1024;
#pragma unroll
    for (int j = 0; j < 4; ++j) {
      int gcol = bn * 128 + wc * 64 + j * 16 + cl;
#pragma unroll
      for (int i = 0; i < 4; ++i) {
        int grow = bm * 128 + wr * 64 + i * 16 + rq * 4;
#pragma unroll
        for (int reg = 0; reg < 4; ++reg)
          Pp[(size_t)(grow + reg) * 1024 + gcol] = (bf16_t)acc[i][j][reg];
      }
    }
  } else {
#pragma unroll
    for (int j = 0; j < 4; ++j) {
      int gcol = bn * 128 + wc * 64 + j * 16 + cl;
      float bv = bias[gcol];
#pragma unroll
      for (int i = 0; i < 4; ++i) {
        int grow = bm * 128 + wr * 64 + i * 16 + rq * 4;
#pragma unroll
        for (int reg = 0; reg < 4; ++reg) {
          float v = acc[i][j][reg] + bv;
          v = v > 0.0f ? v : 0.0f;
          C[(size_t)(grow + reg) * 1024 + gcol] = (bf16_t)v;
        }
      }
    }
  }
}

// ---------------- mid GEMM: 64x128 tile, BK=64, NB=3 depth-2, 3-bit XOR swizzle ----
// 16 MFMA per barrier; half the per-step overhead of BK=32 (round-14: -11us on mids).
template <bool SPLIT>
__global__ __launch_bounds__(256, 2) void k_gemm64(
    const bf16_t* __restrict__ A, const bf16_t* __restrict__ Bw,
    const float* __restrict__ bias, bf16_t* __restrict__ C,
    bf16_t* __restrict__ P, int M, int Kstride, int kchunk) {
  constexpr int VM = 6;                       // loads/thread/stage: A 2 + B 4
  constexpr int NB = 3;                       // 72 KB LDS -> 2 blocks/CU
  __shared__ bf16_t As[NB][64 * 64];
  __shared__ bf16_t Bs[NB][128 * 64];

  const int tid = threadIdx.x;
  const int lane = tid & 63;
  const int wave = tid >> 6;
  const int wr = wave >> 1, wc = wave & 1;
  const int bm = blockIdx.x, bn = blockIdx.y, bz = blockIdx.z;

  const bf16_t* Abase = A + (size_t)bm * 64 * Kstride + (size_t)bz * kchunk;
  const bf16_t* Bbase = Bw + (size_t)bn * 128 * Kstride + (size_t)bz * kchunk;

  f32x4 acc[2][4] = {};
  const int rl = lane & 15, kq = lane >> 4;

  auto stage = [&](int buf, int ko) {
#pragma unroll
    for (int it = 0; it < 2; ++it) {          // A: 64 rows x 8 chunks = 512
      int c = tid + 256 * it;
      int r = c >> 3, ch = c & 7;
      int kb = ch ^ ((r >> 1) & 7);           // inverse 3-bit swizzle on source
      GLD_LDS16(Abase + (size_t)r * Kstride + ko + kb * 8, &As[buf][c * 8]);
    }
#pragma unroll
    for (int it = 0; it < 4; ++it) {          // B: 128 rows x 8 chunks = 1024
      int c = tid + 256 * it;
      int r = c >> 3, ch = c & 7;
      int kb = ch ^ ((r >> 1) & 7);
      GLD_LDS16(Bbase + (size_t)r * Kstride + ko + kb * 8, &Bs[buf][c * 8]);
    }
  };

  const int kiters = kchunk >> 6;
  stage(0, 0);
  if (kiters > 1) stage(1, 64);

  int cur = 0;
  for (int t = 0; t < kiters; ++t) {
    const int nin = kiters - 1 - t;
    if (nin >= 1) asm volatile("s_waitcnt vmcnt(%0)" :: "i"(VM) : "memory");
    else          asm volatile("s_waitcnt vmcnt(0)" ::: "memory");
    __builtin_amdgcn_s_barrier();
    __builtin_amdgcn_sched_barrier(0);
    if (t + 2 < kiters) {
      int b2 = cur + 2; if (b2 >= 3) b2 -= 3;
      stage(b2, (t + 2) * 64);
    }
#pragma unroll
    for (int kk = 0; kk < 2; ++kk) {          // two K=32 windows per tile
      bf16x8 af[2], bfr[4];
#pragma unroll
      for (int i = 0; i < 2; ++i) {
        int r = wr * 32 + i * 16 + rl;
        int ch = ((kk << 2) | kq) ^ ((r >> 1) & 7);
        af[i] = *reinterpret_cast<const bf16x8*>(&As[cur][r * 64 + ch * 8]);
      }
#pragma unroll
      for (int j = 0; j < 4; ++j) {
        int r = wc * 64 + j * 16 + rl;
        int ch = ((kk << 2) | kq) ^ ((r >> 1) & 7);
        bfr[j] = *reinterpret_cast<const bf16x8*>(&Bs[cur][r * 64 + ch * 8]);
      }
#pragma unroll
      for (int i = 0; i < 2; ++i)
#pragma unroll
        for (int j = 0; j < 4; ++j)
          acc[i][j] = __builtin_amdgcn_mfma_f32_16x16x32_bf16(af[i], bfr[j], acc[i][j], 0, 0, 0);
    }
    if (++cur >= 3) cur = 0;
  }

  const int rq = lane >> 4, cl = lane & 15;
  if (SPLIT) {
    bf16_t* Pp = P + (size_t)bz * M * 1024;
#pragma unroll
    for (int j = 0; j < 4; ++j) {
      int gcol = bn * 128 + wc * 64 + j * 16 + cl;
#pragma unroll
      for (int i = 0; i < 2; ++i) {
        int grow = bm * 64 + wr * 32 + i * 16 + rq * 4;
#pragma unroll
        for (int reg = 0; reg < 4; ++reg)
          if (grow + reg < M)
            Pp[(size_t)(grow + reg) * 1024 + gcol] = (bf16_t)acc[i][j][reg];
      }
    }
  } else {
#pragma unroll
    for (int j = 0; j < 4; ++j) {
      int gcol = bn * 128 + wc * 64 + j * 16 + cl;
      float bv = bias[gcol];
#pragma unroll
      for (int i = 0; i < 2; ++i) {
        int grow = bm * 64 + wr * 32 + i * 16 + rq * 4;
#pragma unroll
        for (int reg = 0; reg < 4; ++reg) {
          float v = acc[i][j][reg] + bv;
          v = v > 0.0f ? v : 0.0f;
          C[(size_t)(grow + reg) * 1024 + gcol] = (bf16_t)v;
        }
      }
    }
  }
}

// ---------------- split-K reduce: C = relu(sum_z P[z] + bias), bf16 partials --------
__global__ __launch_bounds__(256) void k_reduce(const bf16_t* __restrict__ P,
                                                const float* __restrict__ bias,
                                                bf16_t* __restrict__ C, int M, int ks) {
  constexpr int N = 1024;
  int idx = blockIdx.x * 256 + threadIdx.x;
  int col = (idx * 4) & (N - 1);
  int row = (idx * 4) >> 10;
  float s0 = 0.0f, s1 = 0.0f, s2 = 0.0f, s3 = 0.0f;
  for (int z = 0; z < ks; ++z) {
    bf16x4 v = *reinterpret_cast<const bf16x4*>(P + ((size_t)z * M + row) * N + col);
    s0 += (float)v[0]; s1 += (float)v[1]; s2 += (float)v[2]; s3 += (float)v[3];
  }
  float4 b = *reinterpret_cast<const float4*>(bias + col);
  bf16x4 o;
  o[0] = (bf16_t)fmaxf(s0 + b.x, 0.0f);
  o[1] = (bf16_t)fmaxf(s1 + b.y, 0.0f);
  o[2] = (bf16_t)fmaxf(s2 + b.z, 0.0f);
  o[3] = (bf16_t)fmaxf(s3 + b.w, 0.0f);
  reinterpret_cast<bf16x4*>(C)[idx] = o;
}

// ---------------- small-M GEMV (M<=16): wave computes 8 rows x 1 col ----------------
template <int KK, bool RELU, bool F32OUT>
__global__ __launch_bounds__(256) void k_tail(const bf16_t* __restrict__ A,
                                              const bf16_t* __restrict__ Bw,
                                              const float* __restrict__ bias,
                                              void* __restrict__ Cout, int M) {
  constexpr int N = 1024;
  constexpr int KPL = KK / 64;
  const int lane = threadIdx.x & 63;
  const int gw = blockIdx.x * 4 + (threadIdx.x >> 6);
  const int n = gw & (N - 1);
  const int mbase = (gw >> 10) * 8;
  const int k0 = lane * KPL;

  float bv[KPL];
  const bf16_t* bp = Bw + (size_t)n * KK + k0;
#pragma unroll
  for (int q = 0; q < KPL / 8; ++q) {
    bf16x8 v = *reinterpret_cast<const bf16x8*>(bp + q * 8);
#pragma unroll
    for (int j = 0; j < 8; ++j) bv[q * 8 + j] = (float)v[j];
  }

  float acc[8];
#pragma unroll
  for (int m = 0; m < 8; ++m) {
    const bf16_t* ap = A + (size_t)(mbase + m) * KK + k0;
    float s = 0.0f;
#pragma unroll
    for (int q = 0; q < KPL / 8; ++q) {
      bf16x8 v = *reinterpret_cast<const bf16x8*>(ap + q * 8);
#pragma unroll
      for (int j = 0; j < 8; ++j) s += (float)v[j] * bv[q * 8 + j];
    }
    acc[m] = s;
  }
#pragma unroll
  for (int m = 0; m < 8; ++m) {
#pragma unroll
    for (int off = 32; off >= 1; off >>= 1) acc[m] += __shfl_xor(acc[m], off, 64);
  }
  if (lane < 8 && mbase + lane < M) {
    float v = acc[lane] + bias[n];
    if (RELU) v = v > 0.0f ? v : 0.0f;
    if (F32OUT) ((float*)Cout)[(size_t)(mbase + lane) * N + n] = v;
    else        ((bf16_t*)Cout)[(size_t)(mbase + lane) * N + n] = (bf16_t)v;
  }
}

// ---------------- log_softmax over 8 rows x 1024 (tiny) ----------------
__global__ __launch_bounds__(256) void k_logsoftmax(const float* __restrict__ logits,
                                                    float* __restrict__ out) {
  int b = blockIdx.x;
  const float* x = logits + b * 1024;
  int tid = threadIdx.x;
  int wave = tid >> 6, lane = tid & 63;
  __shared__ float red[8];

  float m = -1e30f;
  for (int i = tid; i < 1024; i += 256) m = fmaxf(m, x[i]);
#pragma unroll
  for (int off = 32; off >= 1; off >>= 1) m = fmaxf(m, __shfl_xor(m, off, 64));
  if (lane == 0) red[wave] = m;
  __syncthreads();
  m = fmaxf(fmaxf(red[0], red[1]), fmaxf(red[2], red[3]));
  float s = 0.0f;
  for (int i = tid; i < 1024; i += 256) s += expf(x[i] - m);
#pragma unroll
  for (int off = 32; off >= 1; off >>= 1) s += __shfl_xor(s, off, 64);
  if (lane == 0) red[wave] = s;
  __syncthreads();
  float lse = m + logf(red[0] + red[1] + red[2] + red[3]);
  for (int i = tid; i < 1024; i += 256) out[b * 1024 + i] = x[i] - lse;
}

// ---------------- launch ----------------
extern "C" void kernel_launch(void* const* d_in, const int* in_sizes, int n_in,
                              void* d_out, int out_size, void* d_ws, size_t ws_size,
                              hipStream_t stream) {
  const float* leaves = (const float*)d_in[0];
  const float* V_w = (const float*)d_in[1];
  const float* V_b = (const float*)d_in[2];
  const float* U_w = (const float*)d_in[3];
  const float* U_b = (const float*)d_in[4];
  const float* W_w = (const float*)d_in[5];
  const float* W_b = (const float*)d_in[6];
  const float* O_w = (const float*)d_in[7];
  const float* O_b = (const float*)d_in[8];
  float* out = (float*)d_out;

  char* ws = (char*)d_ws;
  size_t off = 0;
  auto alloc = [&](size_t bytes) -> void* {
    off = (off + 255) & ~(size_t)255;
    void* p = ws + off;
    off += bytes;
    return p;
  };

  const size_t MB16 = (size_t)8192 * 1024 * 2;
  bf16_t* leaves_bf = (bf16_t*)alloc(MB16);
  bf16_t* Vw_bf = (bf16_t*)alloc((size_t)1024 * 1024 * 2);
  bf16_t* UW_bf = (bf16_t*)alloc((size_t)2 * 1024 * 1024 * 2);
  bf16_t* Ow_bf = (bf16_t*)alloc((size_t)1024 * 1024 * 2);
  float* buw = (float*)alloc(1024 * 4);
  bf16_t* hA = (bf16_t*)alloc(MB16);
  float* logits = (float*)alloc(8 * 1024 * 4);
  bf16_t* Pbuf = (bf16_t*)alloc((size_t)8 * 4096 * 1024 * 2);   // bf16 partials
  (void)ws_size; (void)in_sizes; (void)n_in; (void)out_size;

  // 1: fused converts
  k_cvt_all<<<2048, 256, 0, stream>>>(leaves, V_w, O_w, U_w, W_w, U_b, W_b,
                                      leaves_bf, Vw_bf, Ow_bf, UW_bf, buw);

  // 2: L0 GEMM 8192x1024, K=1024, BK=32 128x128 depth-4 -> grid(64,8)
  k_gemm<false><<<dim3(64, 8), 256, 0, stream>>>(
      leaves_bf, Vw_bf, V_b, hA, nullptr, 8192, 1024, 1024);

  bf16_t* src = hA;
  bf16_t* dst = leaves_bf;
  auto swap = [&]() { bf16_t* t = src; src = dst; dst = t; };

  // 3: M=4096, K=2048, BK=32 128x128 split-K2 -> grid(32,8,2)
  k_gemm<true><<<dim3(32, 8, 2), 256, 0, stream>>>(
      src, UW_bf, nullptr, nullptr, Pbuf, 4096, 2048, 1024);
  k_reduce<<<4096 * 1024 / 4 / 256, 256, 0, stream>>>(Pbuf, buw, dst, 4096, 2);
  swap();
  // 4: M=2048 BK=64 split-K2 -> grid(32,8,2) = 512 blocks, 16 steps
  k_gemm64<true><<<dim3(32, 8, 2), 256, 0, stream>>>(
      src, UW_bf, nullptr, nullptr, Pbuf, 2048, 2048, 1024);
  k_reduce<<<2048 * 1024 / 4 / 256, 256, 0, stream>>>(Pbuf, buw, dst, 2048, 2);
  swap();
  // 5: M=1024 BK=64 split-K4 -> 512 blocks, 8 steps
  k_gemm64<true><<<dim3(16, 8, 4), 256, 0, stream>>>(
      src, UW_bf, nullptr, nullptr, Pbuf, 1024, 2048, 512);
  k_reduce<<<1024 * 1024 / 4 / 256, 256, 0, stream>>>(Pbuf, buw, dst, 1024, 4);
  swap();
  // 6: M=512 BK=64 split-K4 -> 256 blocks
  k_gemm64<true><<<dim3(8, 8, 4), 256, 0, stream>>>(
      src, UW_bf, nullptr, nullptr, Pbuf, 512, 2048, 512);
  k_reduce<<<512 * 1024 / 4 / 256, 256, 0, stream>>>(Pbuf, buw, dst, 512, 4);
  swap();
  // 7: M=256 BK=64 split-K8 -> 256 blocks, 4 steps
  k_gemm64<true><<<dim3(4, 8, 8), 256, 0, stream>>>(
      src, UW_bf, nullptr, nullptr, Pbuf, 256, 2048, 256);
  k_reduce<<<256 * 1024 / 4 / 256, 256, 0, stream>>>(Pbuf, buw, dst, 256, 8);
  swap();
  // 8: M=128 BK=64 split-K8 -> 128 blocks
  k_gemm64<true><<<dim3(2, 8, 8), 256, 0, stream>>>(
      src, UW_bf, nullptr, nullptr, Pbuf, 128, 2048, 256);
  k_reduce<<<128 * 1024 / 4 / 256, 256, 0, stream>>>(Pbuf, buw, dst, 128, 8);
  swap();
  // 9: M=64 BK=64 split-K16 -> 128 blocks, 2 steps
  k_gemm64<true><<<dim3(1, 8, 16), 256, 0, stream>>>(
      src, UW_bf, nullptr, nullptr, Pbuf, 64, 2048, 128);
  k_reduce<<<64 * 1024 / 4 / 256, 256, 0, stream>>>(Pbuf, buw, dst, 64, 16);
  swap();
  // 10: M=32 BK=64 split-K16 (row-guarded) -> 128 blocks
  k_gemm64<true><<<dim3(1, 8, 16), 256, 0, stream>>>(
      src, UW_bf, nullptr, nullptr, Pbuf, 32, 2048, 128);
  k_reduce<<<32 * 1024 / 4 / 256, 256, 0, stream>>>(Pbuf, buw, dst, 32, 16);
  swap();
  // 11-12: tails M=16, 8
  for (int M = 16; M >= 8; M >>= 1) {
    int blocks = (M / 8) * 1024 / 4;
    k_tail<2048, true, false><<<blocks, 256, 0, stream>>>(src, UW_bf, buw, dst, M);
    swap();
  }

  // 13: logits (M=8, K=1024, fp32 out) -> 256 blocks
  k_tail<1024, false, true><<<256, 256, 0, stream>>>(src, Ow_bf, O_b, logits, 8);
  // 14: log_softmax
  k_logsoftmax<<<8, 256, 0, stream>>>(logits, out);
}